// Round 3
// baseline (1064.822 us; speedup 1.0000x reference)
//
#include <hip/hip_runtime.h>

typedef unsigned short u16;
typedef unsigned int   u32;
typedef __attribute__((ext_vector_type(8))) short s8v;   // 8 bf16 = 4 VGPRs
typedef __attribute__((ext_vector_type(4))) float f4v;

#define OUT1_OFF 21248    // (256,83) elements before new_h
#define OUT2_OFF 152320   // + (1,256,512) elements before attn_weights

__device__ __forceinline__ float b2f(u16 u) { return __uint_as_float(((u32)u) << 16); }
__device__ __forceinline__ u16 f2b(float f) {
  u32 x = __float_as_uint(f);
  x += 0x7fffu + ((x >> 16) & 1u);
  return (u16)(x >> 16);
}
__device__ __forceinline__ float ldf(const void* p, int i, int f32) {
  return f32 ? ((const float*)p)[i] : b2f(((const u16*)p)[i]);
}
__device__ __forceinline__ void stf(void* p, int i, float v, int f32) {
  if (f32) ((float*)p)[i] = v;
  else     ((u16*)p)[i] = f2b(v);
}
__device__ __forceinline__ float tanh_fast(float x) {
  float e = __expf(2.f * x);
  return 1.f - 2.f * __builtin_amdgcn_rcpf(e + 1.f);
}
__device__ __forceinline__ float sigmoid_fast(float x) {
  return __builtin_amdgcn_rcpf(1.f + __expf(-x));
}

// ---------------- dtype detector: bf16 vs f32 ----------------
__global__ __launch_bounds__(64) void k_detect(const u32* __restrict__ hid, int* __restrict__ flag) {
  int lane = threadIdx.x;
  int cnt = 0;
#pragma unroll
  for (int i = 0; i < 8; i++) {
    u32 w = hid[lane * 8 + i];
    u32 e = (w >> 7) & 0xFF;
    cnt += (e >= 100 && e <= 135) ? 1 : 0;
  }
#pragma unroll
  for (int o = 32; o > 0; o >>= 1) cnt += __shfl_xor(cnt, o);
  if (lane == 0) *flag = (cnt < 400) ? 1 : 0;   // 1 = float32 inputs
}

// ---------------- W_ep (512x512, [k][n]) -> Wt [n][k], canonical bf16 ----------------
__global__ __launch_bounds__(256) void k_transpose(const void* __restrict__ in, u16* __restrict__ out,
                                                   const int* __restrict__ flagp) {
  const int f32 = *flagp;
  __shared__ u16 tile[32][33];
  const int bx = blockIdx.x * 32;
  const int by = blockIdx.y * 32;
  const int tx = threadIdx.x, ty = threadIdx.y;
#pragma unroll
  for (int i = 0; i < 4; i++)
    tile[ty + i * 8][tx] = f2b(ldf(in, (by + ty + i * 8) * 512 + bx + tx, f32));
  __syncthreads();
#pragma unroll
  for (int i = 0; i < 4; i++)
    out[(bx + ty + i * 8) * 512 + by + tx] = tile[tx][ty + i * 8];
}

// ---------------- ha2[b][n] = hidden[b]@W_hp + b_hp + b_ep ----------------
__global__ __launch_bounds__(256) void k_hidden_attn(const void* __restrict__ hidden,
                                                     const void* __restrict__ W_hp,
                                                     const void* __restrict__ b_hp,
                                                     const void* __restrict__ b_ep,
                                                     float* __restrict__ ha2,
                                                     const int* __restrict__ flagp) {
  const int f32 = *flagp;
  const int b0 = blockIdx.x * 8, tid = threadIdx.x;
  __shared__ __align__(16) float hh[512 * 8];
  for (int idx = tid; idx < 4096; idx += 256) {
    int k = idx >> 3, j = idx & 7;
    hh[idx] = ldf(hidden, (b0 + j) * 512 + k, f32);
  }
  __syncthreads();
  const int n0 = tid, n1 = tid + 256;
  float acc0[8], acc1[8];
#pragma unroll
  for (int j = 0; j < 8; j++) { acc0[j] = 0.f; acc1[j] = 0.f; }
  for (int k = 0; k < 512; k++) {
    float w0 = ldf(W_hp, k * 512 + n0, f32);
    float w1 = ldf(W_hp, k * 512 + n1, f32);
    const f4v* hp = (const f4v*)&hh[k * 8];
    f4v ha = hp[0], hb = hp[1];
#pragma unroll
    for (int j = 0; j < 4; j++) {
      acc0[j] += ha[j] * w0; acc1[j] += ha[j] * w1;
      acc0[j + 4] += hb[j] * w0; acc1[j + 4] += hb[j] * w1;
    }
  }
  const float bb0 = ldf(b_hp, n0, f32) + ldf(b_ep, n0, f32);
  const float bb1 = ldf(b_hp, n1, f32) + ldf(b_ep, n1, f32);
#pragma unroll
  for (int j = 0; j < 8; j++) {
    ha2[(b0 + j) * 512 + n0] = acc0[j] + bb0;
    ha2[(b0 + j) * 512 + n1] = acc1[j] + bb1;
  }
}

// ---------------- fused scores ----------------
__global__ __launch_bounds__(256) void k_scores(const void* __restrict__ enc,
                                                const u16* __restrict__ Wt,
                                                const float* __restrict__ ha2,
                                                const void* __restrict__ w_v,
                                                float* __restrict__ partial,
                                                const int* __restrict__ flagp) {
  const int f32 = *flagp;
  __shared__ __align__(16) short As[128 * 64];
  __shared__ __align__(16) short Bs[128 * 64];
  const int tid = threadIdx.x;
  const int ntile = blockIdx.x;
  const int mtile = blockIdx.y;
  const int lane = tid & 63, wave = tid >> 6;
  const int wm = wave >> 1, wn = wave & 1;
  const int lane15 = lane & 15, quad = lane >> 4;

  const u16*   Ab = (const u16*)enc + (size_t)mtile * 128 * 512;
  const float* Af = (const float*)enc + (size_t)mtile * 128 * 512;
  const u16*   Bbase = Wt + (size_t)ntile * 128 * 512;

  int srow[4], sslot[4], skc[4];
#pragma unroll
  for (int c = 0; c < 4; c++) {
    int chunk = c * 256 + tid;
    srow[c] = chunk >> 3;
    sslot[c] = chunk & 7;
    skc[c] = sslot[c] ^ (srow[c] & 7);
  }

  int arow[4], brow[4];
#pragma unroll
  for (int i = 0; i < 4; i++) {
    arow[i] = wm * 64 + i * 16 + lane15;
    brow[i] = wn * 64 + i * 16 + lane15;
  }

  f4v acc[4][4];
#pragma unroll
  for (int i = 0; i < 4; i++)
#pragma unroll
    for (int j = 0; j < 4; j++) acc[i][j] = (f4v){0.f, 0.f, 0.f, 0.f};

  for (int k0 = 0; k0 < 512; k0 += 64) {
    s8v ga[4], gb[4];
    if (f32) {
#pragma unroll
      for (int c = 0; c < 4; c++) {
        const float* s = Af + k0 + srow[c] * 512 + skc[c] * 8;
        f4v lo = *(const f4v*)s, hi = *(const f4v*)(s + 4);
        s8v t;
#pragma unroll
        for (int j = 0; j < 4; j++) { t[j] = (short)f2b(lo[j]); t[j + 4] = (short)f2b(hi[j]); }
        ga[c] = t;
      }
    } else {
#pragma unroll
      for (int c = 0; c < 4; c++) ga[c] = *(const s8v*)(Ab + k0 + srow[c] * 512 + skc[c] * 8);
    }
#pragma unroll
    for (int c = 0; c < 4; c++) gb[c] = *(const s8v*)(Bbase + k0 + srow[c] * 512 + skc[c] * 8);
#pragma unroll
    for (int c = 0; c < 4; c++) *(s8v*)&As[srow[c] * 64 + sslot[c] * 8] = ga[c];
#pragma unroll
    for (int c = 0; c < 4; c++) *(s8v*)&Bs[srow[c] * 64 + sslot[c] * 8] = gb[c];
    __syncthreads();
#pragma unroll
    for (int kk2 = 0; kk2 < 2; kk2++) {
      s8v av[4], bv[4];
#pragma unroll
      for (int i = 0; i < 4; i++) {
        int r = arow[i];
        int kc = (kk2 * 4 + quad) ^ (r & 7);
        av[i] = *(const s8v*)&As[r * 64 + kc * 8];
      }
#pragma unroll
      for (int j = 0; j < 4; j++) {
        int r = brow[j];
        int kc = (kk2 * 4 + quad) ^ (r & 7);
        bv[j] = *(const s8v*)&Bs[r * 64 + kc * 8];
      }
#pragma unroll
      for (int i = 0; i < 4; i++)
#pragma unroll
        for (int j = 0; j < 4; j++)
          acc[i][j] = __builtin_amdgcn_mfma_f32_16x16x32_bf16(av[i], bv[j], acc[i][j], 0, 0, 0);
    }
    __syncthreads();
  }

  float wv[4]; int ng[4];
#pragma unroll
  for (int j = 0; j < 4; j++) {
    ng[j] = ntile * 128 + wn * 64 + j * 16 + lane15;
    wv[j] = ldf(w_v, ng[j], f32);
  }
#pragma unroll
  for (int i = 0; i < 4; i++) {
#pragma unroll
    for (int r = 0; r < 4; r++) {
      int mg = mtile * 128 + wm * 64 + i * 16 + quad * 4 + r;
      int bb = mg & 255, tt = mg >> 8;
      const float* hrow = ha2 + bb * 512;
      float s = 0.f;
#pragma unroll
      for (int j = 0; j < 4; j++)
        s += tanh_fast(acc[i][j][r] + hrow[ng[j]]) * wv[j];
      s += __shfl_xor(s, 1); s += __shfl_xor(s, 2);
      s += __shfl_xor(s, 4); s += __shfl_xor(s, 8);
      if (lane15 == 0) partial[(bb * 600 + tt) * 8 + ntile * 2 + wn] = s;
    }
  }
}

// ---------------- softmax over T per batch; writes attn (ws) + output 2 ----------------
__global__ __launch_bounds__(256) void k_softmax(const float* __restrict__ partial,
                                                 float* __restrict__ attn,
                                                 void* __restrict__ dout,
                                                 const int* __restrict__ flagp) {
  const int f32 = *flagp;
  const int b = blockIdx.x, tid = threadIdx.x;
  float sv[3];
  float m = -1e30f;
#pragma unroll
  for (int ii = 0; ii < 3; ii++) {
    int t = tid + ii * 256;
    float s = -1e30f;
    if (t < 600) {
      const float* p = partial + (size_t)(b * 600 + t) * 8;
      s = ((p[0] + p[1]) + (p[2] + p[3])) + ((p[4] + p[5]) + (p[6] + p[7]));
    }
    sv[ii] = s;
    m = fmaxf(m, s);
  }
#pragma unroll
  for (int o = 32; o > 0; o >>= 1) m = fmaxf(m, __shfl_xor(m, o));
  __shared__ float red[4], redsum[4];
  if ((tid & 63) == 0) red[tid >> 6] = m;
  __syncthreads();
  m = fmaxf(fmaxf(red[0], red[1]), fmaxf(red[2], red[3]));
  float lsum = 0.f, ev[3];
#pragma unroll
  for (int ii = 0; ii < 3; ii++) {
    int t = tid + ii * 256;
    float e = (t < 600) ? __expf(sv[ii] - m) : 0.f;
    ev[ii] = e;
    lsum += e;
  }
#pragma unroll
  for (int o = 32; o > 0; o >>= 1) lsum += __shfl_xor(lsum, o);
  if ((tid & 63) == 0) redsum[tid >> 6] = lsum;
  __syncthreads();
  float inv = 1.f / (redsum[0] + redsum[1] + redsum[2] + redsum[3]);
#pragma unroll
  for (int ii = 0; ii < 3; ii++) {
    int t = tid + ii * 256;
    if (t < 600) {
      float a = ev[ii] * inv;
      attn[b * 600 + t] = a;
      stf(dout, OUT2_OFF + b * 600 + t, a, f32);
    }
  }
}

// ---------------- context partials ----------------
__global__ __launch_bounds__(256) void k_context(const void* __restrict__ enc,
                                                 const float* __restrict__ attn,
                                                 float* __restrict__ part,
                                                 const int* __restrict__ flagp) {
  const int f32 = *flagp;
  const int b = blockIdx.x, ch = blockIdx.y, tid = threadIdx.x;
  float ax = 0.f, ay = 0.f;
  const int t0 = ch * 75;
  if (f32) {
    const float* ef = (const float*)enc;
    for (int t = t0; t < t0 + 75; t++) {
      float w = attn[b * 600 + t];
      float2 pv = *(const float2*)&ef[((size_t)(t * 256 + b)) * 512 + tid * 2];
      ax += w * pv.x;
      ay += w * pv.y;
    }
  } else {
    const u16* eb = (const u16*)enc;
    for (int t = t0; t < t0 + 75; t++) {
      float w = attn[b * 600 + t];
      u32 pv = *(const u32*)&eb[((size_t)(t * 256 + b)) * 512 + tid * 2];
      ax += w * b2f((u16)(pv & 0xffff));
      ay += w * b2f((u16)(pv >> 16));
    }
  }
  float2 o; o.x = ax; o.y = ay;
  *(float2*)&part[((size_t)(ch * 256 + b)) * 512 + tid * 2] = o;
}

// ---------------- argmax + embed + context@W_cs -> in_dec[b][300] ----------------
__global__ __launch_bounds__(256) void k_decode_pre(const void* __restrict__ in_char,
                                                    const float* __restrict__ part,
                                                    const void* __restrict__ W_cs,
                                                    const void* __restrict__ b_cs,
                                                    const void* __restrict__ emb,
                                                    float* __restrict__ indec,
                                                    const int* __restrict__ flagp) {
  const int f32 = *flagp;
  const int b = blockIdx.x, tid = threadIdx.x;
  __shared__ float ctx[512];
  __shared__ int topi;
  for (int h = tid; h < 512; h += 256) {
    float s = 0.f;
#pragma unroll
    for (int c = 0; c < 8; c++) s += part[((size_t)(c * 256 + b)) * 512 + h];
    ctx[h] = s;
  }
  if (tid == 0) {
    float best = -1e30f; int bi = 0;
    for (int i = 0; i < 83; i++) {
      float v = ldf(in_char, b * 83 + i, f32);
      if (v > best) { best = v; bi = i; }
    }
    topi = bi;
  }
  __syncthreads();
  if (tid < 50) indec[b * 300 + tid] = ldf(emb, topi * 50 + tid, f32);
  if (tid < 250) {
    float acc = ldf(b_cs, tid, f32);
    for (int k = 0; k < 512; k++) acc += ctx[k] * ldf(W_cs, k * 250 + tid, f32);
    indec[b * 300 + 50 + tid] = acc;
  }
}

// ---------------- GRU input/hidden gates ----------------
__global__ __launch_bounds__(256) void k_gates(const float* __restrict__ indec,
                                               const void* __restrict__ hidden,
                                               const void* __restrict__ W_ih,
                                               const void* __restrict__ b_ih,
                                               const void* __restrict__ W_hh,
                                               const void* __restrict__ b_hh,
                                               float* __restrict__ gi,
                                               float* __restrict__ gh,
                                               const int* __restrict__ flagp) {
  const int f32 = *flagp;
  const int tid = threadIdx.x;
  const int n = blockIdx.x * 256 + tid;
  const int b0 = blockIdx.y * 8;
  const int z = blockIdx.z;
  __shared__ __align__(16) float src[512 * 8];
  if (z) {
    for (int idx = tid; idx < 4096; idx += 256) {
      int k = idx >> 3, j = idx & 7;
      src[idx] = ldf(hidden, (b0 + j) * 512 + k, f32);
    }
  } else {
    for (int idx = tid; idx < 2400; idx += 256) {
      int k = idx >> 3, j = idx & 7;
      src[idx] = indec[(b0 + j) * 300 + k];
    }
  }
  __syncthreads();
  const int K = z ? 512 : 300;
  const void* W = z ? W_hh : W_ih;
  const float bias = ldf(z ? b_hh : b_ih, n, f32);
  float acc[8];
#pragma unroll
  for (int j = 0; j < 8; j++) acc[j] = bias;
  for (int k = 0; k < K; k++) {
    float w = ldf(W, k * 1536 + n, f32);
    const f4v* hp = (const f4v*)&src[k * 8];
    f4v h0 = hp[0], h1 = hp[1];
#pragma unroll
    for (int j = 0; j < 4; j++) {
      acc[j] += h0[j] * w;
      acc[j + 4] += h1[j] * w;
    }
  }
  float* dst = z ? gh : gi;
#pragma unroll
  for (int j = 0; j < 8; j++) dst[(b0 + j) * 1536 + n] = acc[j];
}

// ---------------- GRU combine -> new_h (ws) + output 1 ----------------
__global__ __launch_bounds__(512) void k_gru(const float* __restrict__ gi,
                                             const float* __restrict__ gh,
                                             const void* __restrict__ hidden,
                                             float* __restrict__ newh,
                                             void* __restrict__ dout,
                                             const int* __restrict__ flagp) {
  const int f32 = *flagp;
  const int b = blockIdx.x, n = threadIdx.x;
  const float* gib = gi + b * 1536;
  const float* ghb = gh + b * 1536;
  float r = sigmoid_fast(gib[n] + ghb[n]);
  float z = sigmoid_fast(gib[512 + n] + ghb[512 + n]);
  float nn = tanh_fast(gib[1024 + n] + r * ghb[1024 + n]);
  float h = ldf(hidden, b * 512 + n, f32);
  float v = (1.f - z) * nn + z * h;
  newh[b * 512 + n] = v;
  stf(dout, OUT1_OFF + b * 512 + n, v, f32);
}

// ---------------- new_h@W_out + b_out, softmax -> output 0 ----------------
__global__ __launch_bounds__(128) void k_out_softmax(const float* __restrict__ newh,
                                                     const void* __restrict__ W_out,
                                                     const void* __restrict__ b_out,
                                                     void* __restrict__ dout,
                                                     const int* __restrict__ flagp) {
  const int f32 = *flagp;
  const int b = blockIdx.x, tid = threadIdx.x;
  __shared__ float h[512];
  __shared__ float lg[83];
  __shared__ float mx, sm;
  for (int i = tid; i < 512; i += 128) h[i] = newh[b * 512 + i];
  __syncthreads();
  float acc = 0.f;
  if (tid < 83) {
    acc = ldf(b_out, tid, f32);
    for (int k = 0; k < 512; k++) acc += h[k] * ldf(W_out, k * 83 + tid, f32);
    lg[tid] = acc;
  }
  __syncthreads();
  if (tid == 0) {
    float m = -1e30f;
    for (int i = 0; i < 83; i++) m = fmaxf(m, lg[i]);
    mx = m;
  }
  __syncthreads();
  float e = 0.f;
  if (tid < 83) { e = __expf(acc - mx); lg[tid] = e; }
  __syncthreads();
  if (tid == 0) {
    float s = 0.f;
    for (int i = 0; i < 83; i++) s += lg[i];
    sm = s;
  }
  __syncthreads();
  if (tid < 83) stf(dout, b * 83 + tid, e / sm, f32);
}

extern "C" void kernel_launch(void* const* d_in, const int* in_sizes, int n_in,
                              void* d_out, int out_size, void* d_ws, size_t ws_size,
                              hipStream_t stream) {
  const void* in_char = d_in[0];
  const void* hidden  = d_in[1];
  const void* enc     = d_in[2];
  const void* W_hp    = d_in[3];
  const void* b_hp    = d_in[4];
  const void* W_ep    = d_in[5];
  const void* b_ep    = d_in[6];
  const void* w_v     = d_in[7];
  // d_in[8] = b_v: constant shift inside softmax -> cancels, skipped
  const void* W_cs    = d_in[9];
  const void* b_cs    = d_in[10];
  const void* emb     = d_in[11];
  const void* W_ih    = d_in[12];
  const void* b_ih    = d_in[13];
  const void* W_hh    = d_in[14];
  const void* b_hh    = d_in[15];
  const void* W_out   = d_in[16];
  const void* b_out   = d_in[17];

  // workspace layout (lifetime-aliased; peak 7.41 MB)
  char* ws = (char*)d_ws;
  int*   flag  = (int*)(ws);
  u16*   Wt    = (u16*)(ws + 256);
  float* ha2   = (float*)(ws + 524544);
  float* attn  = (float*)(ws + 1048832);
  float* indec = (float*)(ws + 1663232);
  float* newh  = (float*)(ws + 1970432);
  char*  big   = ws + 2494720;             // 4.9 MB shared region
  float* part8 = (float*)big;              // k_scores -> k_softmax
  float* ctxp  = (float*)big;              // k_context -> k_decode_pre
  float* gi    = (float*)big;              // k_gates -> k_gru
  float* gh    = (float*)(big + 1572864);

  k_detect<<<1, 64, 0, stream>>>((const u32*)hidden, flag);
  k_transpose<<<dim3(16, 16), dim3(32, 8), 0, stream>>>(W_ep, Wt, flag);
  k_hidden_attn<<<32, 256, 0, stream>>>(hidden, W_hp, b_hp, b_ep, ha2, flag);
  k_scores<<<dim3(4, 1200), 256, 0, stream>>>(enc, Wt, ha2, w_v, part8, flag);
  k_softmax<<<256, 256, 0, stream>>>(part8, attn, d_out, flag);
  k_context<<<dim3(256, 8), 256, 0, stream>>>(enc, attn, ctxp, flag);
  k_decode_pre<<<256, 256, 0, stream>>>(in_char, ctxp, W_cs, b_cs, emb, indec, flag);
  k_gates<<<dim3(6, 32, 2), 256, 0, stream>>>(indec, hidden, W_ih, b_ih, W_hh, b_hh, gi, gh, flag);
  k_gru<<<256, 512, 0, stream>>>(gi, gh, hidden, newh, d_out, flag);
  k_out_softmax<<<256, 128, 0, stream>>>(newh, W_out, b_out, d_out, flag);
}

// Round 4
// 865.116 us; speedup vs baseline: 1.2308x; 1.2308x over previous
//
#include <hip/hip_runtime.h>

typedef unsigned short u16;
typedef unsigned int   u32;
typedef __attribute__((ext_vector_type(8))) short s8v;   // 8 bf16 = 4 VGPRs
typedef __attribute__((ext_vector_type(4))) float f4v;

#define OUT1_OFF 21248    // (256,83) elements before new_h
#define OUT2_OFF 152320   // + (1,256,512) elements before attn_weights

__device__ __forceinline__ float b2f(u16 u) { return __uint_as_float(((u32)u) << 16); }
__device__ __forceinline__ u16 f2b(float f) {
  u32 x = __float_as_uint(f);
  x += 0x7fffu + ((x >> 16) & 1u);
  return (u16)(x >> 16);
}
__device__ __forceinline__ float tanh_fast(float x) {
  float e = __expf(2.f * x);
  return 1.f - 2.f * __builtin_amdgcn_rcpf(e + 1.f);
}
__device__ __forceinline__ float sigmoid_fast(float x) {
  return __builtin_amdgcn_rcpf(1.f + __expf(-x));
}
__device__ __forceinline__ void gl16(const void* g, void* l) {
  __builtin_amdgcn_global_load_lds((const __attribute__((address_space(1))) u32*)g,
                                   (__attribute__((address_space(3))) u32*)l, 16, 0, 0);
}

// ---------------- enc fp32 -> bf16 (8 els/thread, exact grid) ----------------
__global__ __launch_bounds__(256) void k_prep(const f4v* __restrict__ in, s8v* __restrict__ out) {
  int i = blockIdx.x * 256 + threadIdx.x;
  f4v a = in[2 * i], b = in[2 * i + 1];
  s8v t;
#pragma unroll
  for (int j = 0; j < 4; j++) { t[j] = (short)f2b(a[j]); t[4 + j] = (short)f2b(b[j]); }
  out[i] = t;
}

// ---------------- W_ep (512x512 f32, [k][n]) -> Wt bf16 [n][k] ----------------
__global__ __launch_bounds__(256) void k_transpose(const float* __restrict__ in, u16* __restrict__ out) {
  __shared__ u16 tile[32][33];
  const int bx = blockIdx.x * 32;  // n
  const int by = blockIdx.y * 32;  // k
  const int tx = threadIdx.x, ty = threadIdx.y;  // 32 x 8
#pragma unroll
  for (int i = 0; i < 4; i++)
    tile[ty + i * 8][tx] = f2b(in[(by + ty + i * 8) * 512 + bx + tx]);
  __syncthreads();
#pragma unroll
  for (int i = 0; i < 4; i++)
    out[(bx + ty + i * 8) * 512 + by + tx] = tile[tx][ty + i * 8];
}

// ---------------- ha2[b][n] = hidden[b]@W_hp + b_hp + b_ep (all f32) ----------------
__global__ __launch_bounds__(256) void k_hidden_attn(const float* __restrict__ hidden,
                                                     const float* __restrict__ W_hp,
                                                     const float* __restrict__ b_hp,
                                                     const float* __restrict__ b_ep,
                                                     float* __restrict__ ha2) {
  const int b0 = blockIdx.x * 8, tid = threadIdx.x;
  __shared__ __align__(16) float hh[512 * 8];  // [k][j]
  for (int idx = tid; idx < 4096; idx += 256) {
    int k = idx >> 3, j = idx & 7;
    hh[idx] = hidden[(b0 + j) * 512 + k];
  }
  __syncthreads();
  const int n0 = tid, n1 = tid + 256;
  float acc0[8], acc1[8];
#pragma unroll
  for (int j = 0; j < 8; j++) { acc0[j] = 0.f; acc1[j] = 0.f; }
  for (int k = 0; k < 512; k++) {
    float w0 = W_hp[k * 512 + n0];
    float w1 = W_hp[k * 512 + n1];
    const f4v* hp = (const f4v*)&hh[k * 8];
    f4v ha = hp[0], hb = hp[1];
#pragma unroll
    for (int j = 0; j < 4; j++) {
      acc0[j] += ha[j] * w0; acc1[j] += ha[j] * w1;
      acc0[j + 4] += hb[j] * w0; acc1[j + 4] += hb[j] * w1;
    }
  }
  const float bb0 = b_hp[n0] + b_ep[n0];
  const float bb1 = b_hp[n1] + b_ep[n1];
#pragma unroll
  for (int j = 0; j < 8; j++) {
    ha2[(b0 + j) * 512 + n0] = acc0[j] + bb0;
    ha2[(b0 + j) * 512 + n1] = acc1[j] + bb1;
  }
}

// ---------------- fused scores, bf16 A via global_load_lds ----------------
// 1D grid 4800, XCD-swizzled: id&7 selects XCD-group; 4 sibling ntile-blocks of one
// mtile get consecutive j -> same XCD (round-robin dispatch) -> A-tile L2 reuse.
__global__ __launch_bounds__(256) void k_scores_bf(const u16* __restrict__ encb,
                                                   const u16* __restrict__ Wt,
                                                   const float* __restrict__ ha2,
                                                   const float* __restrict__ w_v,
                                                   float* __restrict__ partial) {
  __shared__ __align__(16) short As[128 * 64];
  __shared__ __align__(16) short Bs[128 * 64];
  const int tid = threadIdx.x;
  const int id = blockIdx.x;
  const int x = id & 7, jj = id >> 3;
  const int mtile = x * 150 + (jj >> 2);
  const int ntile = jj & 3;
  const int lane = tid & 63, wave = tid >> 6;
  const int wm = wave >> 1, wn = wave & 1;
  const int lane15 = lane & 15, quad = lane >> 4;

  const u16* Abase = encb + (size_t)mtile * 128 * 512;
  const u16* Bbase = Wt + (size_t)ntile * 128 * 512;

  int srow[4], skc[4];
#pragma unroll
  for (int c = 0; c < 4; c++) {
    int chunk = c * 256 + tid;          // 16B chunk id, 0..1023
    srow[c] = chunk >> 3;               // 0..127
    skc[c] = (chunk & 7) ^ (srow[c] & 7);  // XOR swizzle in global k-chunk
  }

  int arow[4], brow[4];
#pragma unroll
  for (int i = 0; i < 4; i++) {
    arow[i] = wm * 64 + i * 16 + lane15;
    brow[i] = wn * 64 + i * 16 + lane15;
  }

  f4v acc[4][4];
#pragma unroll
  for (int i = 0; i < 4; i++)
#pragma unroll
    for (int j = 0; j < 4; j++) acc[i][j] = (f4v){0.f, 0.f, 0.f, 0.f};

  for (int k0 = 0; k0 < 512; k0 += 64) {
    const u16* Ak = Abase + k0;
    const u16* Bk = Bbase + k0;
#pragma unroll
    for (int c = 0; c < 4; c++)
      gl16(Ak + srow[c] * 512 + skc[c] * 8, (char*)As + c * 4096 + tid * 16);
#pragma unroll
    for (int c = 0; c < 4; c++)
      gl16(Bk + srow[c] * 512 + skc[c] * 8, (char*)Bs + c * 4096 + tid * 16);
    __syncthreads();
#pragma unroll
    for (int kk2 = 0; kk2 < 2; kk2++) {
      s8v av[4], bv[4];
#pragma unroll
      for (int i = 0; i < 4; i++) {
        int r = arow[i];
        int kc = (kk2 * 4 + quad) ^ (r & 7);
        av[i] = *(const s8v*)&As[r * 64 + kc * 8];
      }
#pragma unroll
      for (int j = 0; j < 4; j++) {
        int r = brow[j];
        int kc = (kk2 * 4 + quad) ^ (r & 7);
        bv[j] = *(const s8v*)&Bs[r * 64 + kc * 8];
      }
#pragma unroll
      for (int i = 0; i < 4; i++)
#pragma unroll
        for (int j = 0; j < 4; j++)
          acc[i][j] = __builtin_amdgcn_mfma_f32_16x16x32_bf16(av[i], bv[j], acc[i][j], 0, 0, 0);
    }
    __syncthreads();
  }

  float wv[4]; int ng[4];
#pragma unroll
  for (int j = 0; j < 4; j++) {
    ng[j] = ntile * 128 + wn * 64 + j * 16 + lane15;
    wv[j] = w_v[ng[j]];
  }
#pragma unroll
  for (int i = 0; i < 4; i++) {
#pragma unroll
    for (int r = 0; r < 4; r++) {
      int mg = mtile * 128 + wm * 64 + i * 16 + quad * 4 + r;  // m = t*256 + b
      int bb = mg & 255, tt = mg >> 8;
      const float* hrow = ha2 + bb * 512;
      float s = 0.f;
#pragma unroll
      for (int j = 0; j < 4; j++)
        s += tanh_fast(acc[i][j][r] + hrow[ng[j]]) * wv[j];
      s += __shfl_xor(s, 1); s += __shfl_xor(s, 2);
      s += __shfl_xor(s, 4); s += __shfl_xor(s, 8);
      if (lane15 == 0) partial[(bb * 600 + tt) * 8 + ntile * 2 + wn] = s;
    }
  }
}

// ---------------- fallback: fused scores, fp32 A with inline cvt ----------------
__global__ __launch_bounds__(256) void k_scores_f32(const float* __restrict__ enc,
                                                    const u16* __restrict__ Wt,
                                                    const float* __restrict__ ha2,
                                                    const float* __restrict__ w_v,
                                                    float* __restrict__ partial) {
  __shared__ __align__(16) short As[128 * 64];
  __shared__ __align__(16) short Bs[128 * 64];
  const int tid = threadIdx.x;
  const int id = blockIdx.x;
  const int x = id & 7, jj = id >> 3;
  const int mtile = x * 150 + (jj >> 2);
  const int ntile = jj & 3;
  const int lane = tid & 63, wave = tid >> 6;
  const int wm = wave >> 1, wn = wave & 1;
  const int lane15 = lane & 15, quad = lane >> 4;

  const float* Af = enc + (size_t)mtile * 128 * 512;
  const u16*   Bbase = Wt + (size_t)ntile * 128 * 512;

  int srow[4], sslot[4], skc[4];
#pragma unroll
  for (int c = 0; c < 4; c++) {
    int chunk = c * 256 + tid;
    srow[c] = chunk >> 3;
    sslot[c] = chunk & 7;
    skc[c] = sslot[c] ^ (srow[c] & 7);
  }
  int arow[4], brow[4];
#pragma unroll
  for (int i = 0; i < 4; i++) {
    arow[i] = wm * 64 + i * 16 + lane15;
    brow[i] = wn * 64 + i * 16 + lane15;
  }
  f4v acc[4][4];
#pragma unroll
  for (int i = 0; i < 4; i++)
#pragma unroll
    for (int j = 0; j < 4; j++) acc[i][j] = (f4v){0.f, 0.f, 0.f, 0.f};

  for (int k0 = 0; k0 < 512; k0 += 64) {
    s8v ga[4], gb[4];
#pragma unroll
    for (int c = 0; c < 4; c++) {
      const float* s = Af + k0 + srow[c] * 512 + skc[c] * 8;
      f4v lo = *(const f4v*)s, hi = *(const f4v*)(s + 4);
      s8v t;
#pragma unroll
      for (int j = 0; j < 4; j++) { t[j] = (short)f2b(lo[j]); t[j + 4] = (short)f2b(hi[j]); }
      ga[c] = t;
    }
#pragma unroll
    for (int c = 0; c < 4; c++) gb[c] = *(const s8v*)(Bbase + k0 + srow[c] * 512 + skc[c] * 8);
#pragma unroll
    for (int c = 0; c < 4; c++) *(s8v*)&As[srow[c] * 64 + sslot[c] * 8] = ga[c];
#pragma unroll
    for (int c = 0; c < 4; c++) *(s8v*)&Bs[srow[c] * 64 + sslot[c] * 8] = gb[c];
    __syncthreads();
#pragma unroll
    for (int kk2 = 0; kk2 < 2; kk2++) {
      s8v av[4], bv[4];
#pragma unroll
      for (int i = 0; i < 4; i++) {
        int r = arow[i];
        int kc = (kk2 * 4 + quad) ^ (r & 7);
        av[i] = *(const s8v*)&As[r * 64 + kc * 8];
      }
#pragma unroll
      for (int j = 0; j < 4; j++) {
        int r = brow[j];
        int kc = (kk2 * 4 + quad) ^ (r & 7);
        bv[j] = *(const s8v*)&Bs[r * 64 + kc * 8];
      }
#pragma unroll
      for (int i = 0; i < 4; i++)
#pragma unroll
        for (int j = 0; j < 4; j++)
          acc[i][j] = __builtin_amdgcn_mfma_f32_16x16x32_bf16(av[i], bv[j], acc[i][j], 0, 0, 0);
    }
    __syncthreads();
  }

  float wv[4]; int ng[4];
#pragma unroll
  for (int j = 0; j < 4; j++) {
    ng[j] = ntile * 128 + wn * 64 + j * 16 + lane15;
    wv[j] = w_v[ng[j]];
  }
#pragma unroll
  for (int i = 0; i < 4; i++) {
#pragma unroll
    for (int r = 0; r < 4; r++) {
      int mg = mtile * 128 + wm * 64 + i * 16 + quad * 4 + r;
      int bb = mg & 255, tt = mg >> 8;
      const float* hrow = ha2 + bb * 512;
      float s = 0.f;
#pragma unroll
      for (int j = 0; j < 4; j++)
        s += tanh_fast(acc[i][j][r] + hrow[ng[j]]) * wv[j];
      s += __shfl_xor(s, 1); s += __shfl_xor(s, 2);
      s += __shfl_xor(s, 4); s += __shfl_xor(s, 8);
      if (lane15 == 0) partial[(bb * 600 + tt) * 8 + ntile * 2 + wn] = s;
    }
  }
}

// ---------------- softmax over T per batch; writes attn (ws) + output 2 (f32) ----------------
__global__ __launch_bounds__(256) void k_softmax(const float* __restrict__ partial,
                                                 float* __restrict__ attn,
                                                 float* __restrict__ out2) {
  const int b = blockIdx.x, tid = threadIdx.x;
  float sv[3];
  float m = -1e30f;
#pragma unroll
  for (int ii = 0; ii < 3; ii++) {
    int t = tid + ii * 256;
    float s = -1e30f;
    if (t < 600) {
      const float* p = partial + (size_t)(b * 600 + t) * 8;
      s = ((p[0] + p[1]) + (p[2] + p[3])) + ((p[4] + p[5]) + (p[6] + p[7]));
    }
    sv[ii] = s;
    m = fmaxf(m, s);
  }
#pragma unroll
  for (int o = 32; o > 0; o >>= 1) m = fmaxf(m, __shfl_xor(m, o));
  __shared__ float red[4], redsum[4];
  if ((tid & 63) == 0) red[tid >> 6] = m;
  __syncthreads();
  m = fmaxf(fmaxf(red[0], red[1]), fmaxf(red[2], red[3]));
  float lsum = 0.f, ev[3];
#pragma unroll
  for (int ii = 0; ii < 3; ii++) {
    int t = tid + ii * 256;
    float e = (t < 600) ? __expf(sv[ii] - m) : 0.f;
    ev[ii] = e;
    lsum += e;
  }
#pragma unroll
  for (int o = 32; o > 0; o >>= 1) lsum += __shfl_xor(lsum, o);
  if ((tid & 63) == 0) redsum[tid >> 6] = lsum;
  __syncthreads();
  float inv = 1.f / (redsum[0] + redsum[1] + redsum[2] + redsum[3]);
#pragma unroll
  for (int ii = 0; ii < 3; ii++) {
    int t = tid + ii * 256;
    if (t < 600) {
      float a = ev[ii] * inv;
      attn[b * 600 + t] = a;
      out2[b * 600 + t] = a;
    }
  }
}

// ---------------- context partials: bf16 enc ----------------
__global__ __launch_bounds__(256) void k_context_bf(const u16* __restrict__ encb,
                                                    const float* __restrict__ attn,
                                                    float* __restrict__ part) {
  const int b = blockIdx.x, ch = blockIdx.y, tid = threadIdx.x;
  float ax = 0.f, ay = 0.f;
  const int t0 = ch * 75;
  for (int t = t0; t < t0 + 75; t++) {
    float w = attn[b * 600 + t];
    u32 pv = *(const u32*)&encb[((size_t)(t * 256 + b)) * 512 + tid * 2];
    ax += w * b2f((u16)(pv & 0xffff));
    ay += w * b2f((u16)(pv >> 16));
  }
  float2 o; o.x = ax; o.y = ay;
  *(float2*)&part[((size_t)(ch * 256 + b)) * 512 + tid * 2] = o;
}

// ---------------- context partials: fp32 enc (fallback) ----------------
__global__ __launch_bounds__(256) void k_context_f32(const float* __restrict__ enc,
                                                     const float* __restrict__ attn,
                                                     float* __restrict__ part) {
  const int b = blockIdx.x, ch = blockIdx.y, tid = threadIdx.x;
  float ax = 0.f, ay = 0.f;
  const int t0 = ch * 75;
  for (int t = t0; t < t0 + 75; t++) {
    float w = attn[b * 600 + t];
    float2 pv = *(const float2*)&enc[((size_t)(t * 256 + b)) * 512 + tid * 2];
    ax += w * pv.x;
    ay += w * pv.y;
  }
  float2 o; o.x = ax; o.y = ay;
  *(float2*)&part[((size_t)(ch * 256 + b)) * 512 + tid * 2] = o;
}

// ---------------- argmax + embed + context@W_cs -> in_dec[b][300] ----------------
__global__ __launch_bounds__(256) void k_decode_pre(const float* __restrict__ in_char,
                                                    const float* __restrict__ part,
                                                    const float* __restrict__ W_cs,
                                                    const float* __restrict__ b_cs,
                                                    const float* __restrict__ emb,
                                                    float* __restrict__ indec) {
  const int b = blockIdx.x, tid = threadIdx.x;
  __shared__ float ctx[512];
  __shared__ int topi;
  for (int h = tid; h < 512; h += 256) {
    float s = 0.f;
#pragma unroll
    for (int c = 0; c < 8; c++) s += part[((size_t)(c * 256 + b)) * 512 + h];
    ctx[h] = s;
  }
  if (tid == 0) {
    float best = -1e30f; int bi = 0;
    for (int i = 0; i < 83; i++) {
      float v = in_char[b * 83 + i];
      if (v > best) { best = v; bi = i; }   // strict > : first max wins (np.argmax)
    }
    topi = bi;
  }
  __syncthreads();
  if (tid < 50) indec[b * 300 + tid] = emb[topi * 50 + tid];
  if (tid < 250) {
    float acc = b_cs[tid];
    for (int k = 0; k < 512; k++) acc += ctx[k] * W_cs[k * 250 + tid];
    indec[b * 300 + 50 + tid] = acc;
  }
}

// ---------------- gi = in_dec@W_ih + b_ih (z=0), gh = h@W_hh + b_hh (z=1) ----------------
__global__ __launch_bounds__(256) void k_gates(const float* __restrict__ indec,
                                               const float* __restrict__ hidden,
                                               const float* __restrict__ W_ih,
                                               const float* __restrict__ b_ih,
                                               const float* __restrict__ W_hh,
                                               const float* __restrict__ b_hh,
                                               float* __restrict__ gi,
                                               float* __restrict__ gh) {
  const int tid = threadIdx.x;
  const int n = blockIdx.x * 256 + tid;
  const int b0 = blockIdx.y * 8;
  const int z = blockIdx.z;
  __shared__ __align__(16) float src[512 * 8];  // [k][j]
  if (z) {
    for (int idx = tid; idx < 4096; idx += 256) {
      int k = idx >> 3, j = idx & 7;
      src[idx] = hidden[(b0 + j) * 512 + k];
    }
  } else {
    for (int idx = tid; idx < 2400; idx += 256) {
      int k = idx >> 3, j = idx & 7;
      src[idx] = indec[(b0 + j) * 300 + k];
    }
  }
  __syncthreads();
  const int K = z ? 512 : 300;
  const float* W = (z ? W_hh : W_ih) + n;
  const float bias = (z ? b_hh : b_ih)[n];
  float acc[8];
#pragma unroll
  for (int j = 0; j < 8; j++) acc[j] = bias;
  for (int k = 0; k < K; k++) {
    float w = W[k * 1536];
    const f4v* hp = (const f4v*)&src[k * 8];
    f4v h0 = hp[0], h1 = hp[1];
#pragma unroll
    for (int j = 0; j < 4; j++) {
      acc[j] += h0[j] * w;
      acc[j + 4] += h1[j] * w;
    }
  }
  float* dst = z ? gh : gi;
#pragma unroll
  for (int j = 0; j < 8; j++) dst[(b0 + j) * 1536 + n] = acc[j];
}

// ---------------- GRU combine -> new_h (ws) + output 1 (f32) ----------------
__global__ __launch_bounds__(512) void k_gru(const float* __restrict__ gi,
                                             const float* __restrict__ gh,
                                             const float* __restrict__ hidden,
                                             float* __restrict__ newh,
                                             float* __restrict__ out1) {
  const int b = blockIdx.x, n = threadIdx.x;
  const float* gib = gi + b * 1536;
  const float* ghb = gh + b * 1536;
  float r = sigmoid_fast(gib[n] + ghb[n]);
  float z = sigmoid_fast(gib[512 + n] + ghb[512 + n]);
  float nn = tanh_fast(gib[1024 + n] + r * ghb[1024 + n]);
  float h = hidden[b * 512 + n];
  float v = (1.f - z) * nn + z * h;
  newh[b * 512 + n] = v;
  out1[b * 512 + n] = v;
}

// ---------------- new_h@W_out + b_out, softmax -> output 0 (f32) ----------------
__global__ __launch_bounds__(128) void k_out_softmax(const float* __restrict__ newh,
                                                     const float* __restrict__ W_out,
                                                     const float* __restrict__ b_out,
                                                     float* __restrict__ out0) {
  const int b = blockIdx.x, tid = threadIdx.x;
  __shared__ float h[512];
  __shared__ float lg[83];
  __shared__ float mx, sm;
  for (int i = tid; i < 512; i += 128) h[i] = newh[b * 512 + i];
  __syncthreads();
  float acc = 0.f;
  if (tid < 83) {
    acc = b_out[tid];
    for (int k = 0; k < 512; k++) acc += h[k] * W_out[k * 83 + tid];
    lg[tid] = acc;
  }
  __syncthreads();
  if (tid == 0) {
    float m = -1e30f;
    for (int i = 0; i < 83; i++) m = fmaxf(m, lg[i]);
    mx = m;
  }
  __syncthreads();
  float e = 0.f;
  if (tid < 83) { e = __expf(acc - mx); lg[tid] = e; }
  __syncthreads();
  if (tid == 0) {
    float s = 0.f;
    for (int i = 0; i < 83; i++) s += lg[i];
    sm = s;
  }
  __syncthreads();
  if (tid < 83) out0[b * 83 + tid] = e / sm;
}

extern "C" void kernel_launch(void* const* d_in, const int* in_sizes, int n_in,
                              void* d_out, int out_size, void* d_ws, size_t ws_size,
                              hipStream_t stream) {
  const float* in_char = (const float*)d_in[0];
  const float* hidden  = (const float*)d_in[1];
  const float* enc     = (const float*)d_in[2];
  const float* W_hp    = (const float*)d_in[3];
  const float* b_hp    = (const float*)d_in[4];
  const float* W_ep    = (const float*)d_in[5];
  const float* b_ep    = (const float*)d_in[6];
  const float* w_v     = (const float*)d_in[7];
  // d_in[8] = b_v: constant shift inside softmax -> cancels, skipped
  const float* W_cs    = (const float*)d_in[9];
  const float* b_cs    = (const float*)d_in[10];
  const float* emb     = (const float*)d_in[11];
  const float* W_ih    = (const float*)d_in[12];
  const float* b_ih    = (const float*)d_in[13];
  const float* W_hh    = (const float*)d_in[14];
  const float* b_hh    = (const float*)d_in[15];
  const float* W_out   = (const float*)d_in[16];
  const float* b_out   = (const float*)d_in[17];

  // workspace layout (lifetime-aliased small region + optional bf16 enc)
  char* ws = (char*)d_ws;
  u16*   Wt    = (u16*)(ws);               // 524288
  float* ha2   = (float*)(ws + 524288);    // 524288
  float* attn  = (float*)(ws + 1048576);   // 614400
  float* indec = (float*)(ws + 1662976);   // 307200
  float* newh  = (float*)(ws + 1970176);   // 524288
  char*  big   = ws + 2494464;             // 4915200 shared region
  float* part8 = (float*)big;              // k_scores -> k_softmax
  float* ctxp  = (float*)big;              // k_context -> k_decode_pre
  float* gi    = (float*)big;              // k_gates -> k_gru
  float* gh    = (float*)(big + 1572864);
  u16*   encb  = (u16*)(ws + 8388608);     // 157286400 (big-ws path only)
  const bool big_ws = ws_size >= (size_t)(8388608 + 157286400);

  float* out0 = (float*)d_out;
  float* out1 = out0 + OUT1_OFF;
  float* out2 = out0 + OUT2_OFF;

  if (big_ws)
    k_prep<<<38400, 256, 0, stream>>>((const f4v*)enc, (s8v*)encb);
  k_transpose<<<dim3(16, 16), dim3(32, 8), 0, stream>>>(W_ep, Wt);
  k_hidden_attn<<<32, 256, 0, stream>>>(hidden, W_hp, b_hp, b_ep, ha2);
  if (big_ws)
    k_scores_bf<<<4800, 256, 0, stream>>>(encb, Wt, ha2, w_v, part8);
  else
    k_scores_f32<<<4800, 256, 0, stream>>>(enc, Wt, ha2, w_v, part8);
  k_softmax<<<256, 256, 0, stream>>>(part8, attn, out2);
  if (big_ws)
    k_context_bf<<<dim3(256, 8), 256, 0, stream>>>(encb, attn, ctxp);
  else
    k_context_f32<<<dim3(256, 8), 256, 0, stream>>>(enc, attn, ctxp);
  k_decode_pre<<<256, 256, 0, stream>>>(in_char, ctxp, W_cs, b_cs, emb, indec);
  k_gates<<<dim3(6, 32, 2), 256, 0, stream>>>(indec, hidden, W_ih, b_ih, W_hh, b_hh, gi, gh);
  k_gru<<<256, 512, 0, stream>>>(gi, gh, hidden, newh, out1);
  k_out_softmax<<<256, 128, 0, stream>>>(newh, W_out, b_out, out0);
}